// Round 1
// baseline (188.666 us; speedup 1.0000x reference)
//
#include <hip/hip_runtime.h>

typedef __bf16 bf16x8 __attribute__((ext_vector_type(8)));
typedef float  f32x4  __attribute__((ext_vector_type(4)));

__device__ inline unsigned short f32_to_bf16(float f) {
    union { float f; unsigned int u; } v; v.f = f;
    unsigned int lsb = (v.u >> 16) & 1u;
    v.u += 0x7fffu + lsb;                 // round-to-nearest-even
    return (unsigned short)(v.u >> 16);
}

__device__ inline void gload_lds16(const void* g, void* l) {
    __builtin_amdgcn_global_load_lds((const __attribute__((address_space(1))) void*)g,
                                     (__attribute__((address_space(3))) void*)l,
                                     16, 0, 0);
}

// ---- pass 1a: x f32 -> bf16, plus per-row sum of squares (f32, exact) ----
__global__ __launch_bounds__(256) void convert_x_kernel(
        const float* __restrict__ x, unsigned short* __restrict__ x16,
        float* __restrict__ x_sq, int D) {
    const int n = blockIdx.x;
    const int t = threadIdx.x;
    const float* xr = x + (size_t)n * D;
    unsigned short* xo = x16 + (size_t)n * D;
    float acc = 0.f;
    for (int p = 0; p < D / 1024; ++p) {
        const int col = p * 1024 + t * 4;
        float4 v = *(const float4*)(xr + col);
        acc += v.x * v.x + v.y * v.y + v.z * v.z + v.w * v.w;
        ushort4 o;
        o.x = f32_to_bf16(v.x); o.y = f32_to_bf16(v.y);
        o.z = f32_to_bf16(v.z); o.w = f32_to_bf16(v.w);
        *(ushort4*)(xo + col) = o;
    }
    for (int off = 32; off; off >>= 1) acc += __shfl_down(acc, off, 64);
    __shared__ float sbuf[4];
    if ((t & 63) == 0) sbuf[t >> 6] = acc;
    __syncthreads();
    if (t == 0) x_sq[n] = sbuf[0] + sbuf[1] + sbuf[2] + sbuf[3];
}

// ---- pass 1b: mu f32 -> bf16 (zero-padded to Cpad rows), plus mu_sq ----
__global__ __launch_bounds__(256) void convert_mu_kernel(
        const float* __restrict__ mu, unsigned short* __restrict__ mu16,
        float* __restrict__ mu_sq, int D, int C) {
    const int c = blockIdx.x;
    const int t = threadIdx.x;
    unsigned short* mo = mu16 + (size_t)c * D;
    if (c >= C) {  // pad rows: zeros (loss pass skips c >= C entirely)
        for (int p = 0; p < D / 1024; ++p) {
            const int col = p * 1024 + t * 4;
            *(ushort4*)(mo + col) = make_ushort4(0, 0, 0, 0);
        }
        if (t == 0) mu_sq[c] = 0.f;
        return;
    }
    const float* mr = mu + (size_t)c * D;
    float acc = 0.f;
    for (int p = 0; p < D / 1024; ++p) {
        const int col = p * 1024 + t * 4;
        float4 v = *(const float4*)(mr + col);
        acc += v.x * v.x + v.y * v.y + v.z * v.z + v.w * v.w;
        ushort4 o;
        o.x = f32_to_bf16(v.x); o.y = f32_to_bf16(v.y);
        o.z = f32_to_bf16(v.z); o.w = f32_to_bf16(v.w);
        *(ushort4*)(mo + col) = o;
    }
    for (int off = 32; off; off >>= 1) acc += __shfl_down(acc, off, 64);
    __shared__ float sbuf[4];
    if ((t & 63) == 0) sbuf[t >> 6] = acc;
    __syncthreads();
    if (t == 0) mu_sq[c] = sbuf[0] + sbuf[1] + sbuf[2] + sbuf[3];
}

// ---- pass 2: cross[n,c] = sum_d x16[n,d] * mu16[c,d]  (B^T GEMM, m97-style) ----
#define BM 128
#define BN 128
#define BK 32

__global__ __launch_bounds__(256) void gemm_kernel(
        const unsigned short* __restrict__ A,  // [M][K] bf16
        const unsigned short* __restrict__ B,  // [Ncols][K] bf16 (mu, B^T layout)
        float* __restrict__ Cm,                // [M][Ncols] f32
        int M, int Ncols, int K) {
    __shared__ __align__(16) unsigned short As[BM * BK];  // [128][32]
    __shared__ __align__(16) unsigned short Bs[BN * BK];

    const int t  = threadIdx.x;
    const int l  = t & 63;
    const int w  = t >> 6;
    const int wr = w >> 1, wc = w & 1;     // 2x2 waves -> 64x64 sub-tiles
    const int lr = l & 15;                 // row/col within 16x16 fragment
    const int kh = l >> 4;                 // k-group: k = kh*8 + i

    const int rowBase = blockIdx.x * BM;   // rows fastest -> B panel L2-resident
    const int colBase = blockIdx.y * BN;

    // staging map: thread t -> row t/4, k-bytes (t%4)*16, linear in LDS (t*16 B)
    const int tr = t >> 2;
    const int tk = (t & 3) * 8;
    const size_t a_goff = (size_t)(rowBase + tr) * K + tk;
    const size_t b_goff = (size_t)(colBase + tr) * K + tk;

    f32x4 zero = {0.f, 0.f, 0.f, 0.f};
    f32x4 acc[4][4];
#pragma unroll
    for (int m = 0; m < 4; ++m)
#pragma unroll
        for (int n = 0; n < 4; ++n) acc[m][n] = zero;

    for (int kk = 0; kk < K; kk += BK) {
        gload_lds16(A + a_goff + kk,            As + t * 8);
        gload_lds16(A + a_goff + 64 * (size_t)K + kk, As + 2048 + t * 8);
        gload_lds16(B + b_goff + kk,            Bs + t * 8);
        gload_lds16(B + b_goff + 64 * (size_t)K + kk, Bs + 2048 + t * 8);
        asm volatile("s_waitcnt vmcnt(0)" ::: "memory");
        __syncthreads();

        bf16x8 af[4], bf[4];
#pragma unroll
        for (int m = 0; m < 4; ++m)
            af[m] = *(const bf16x8*)(As + (wr * 64 + m * 16 + lr) * BK + kh * 8);
#pragma unroll
        for (int n = 0; n < 4; ++n)
            bf[n] = *(const bf16x8*)(Bs + (wc * 64 + n * 16 + lr) * BK + kh * 8);
#pragma unroll
        for (int m = 0; m < 4; ++m)
#pragma unroll
            for (int n = 0; n < 4; ++n)
                acc[m][n] = __builtin_amdgcn_mfma_f32_16x16x32_bf16(af[m], bf[n], acc[m][n], 0, 0, 0);
        __syncthreads();
    }

    // C/D layout (m89-verified): col = lane&15, row = (lane>>4)*4 + reg
#pragma unroll
    for (int m = 0; m < 4; ++m) {
        const int row = rowBase + wr * 64 + m * 16 + kh * 4;
#pragma unroll
        for (int n = 0; n < 4; ++n) {
            const int col = colBase + wc * 64 + n * 16 + lr;
#pragma unroll
            for (int j = 0; j < 4; ++j)
                Cm[(size_t)(row + j) * Ncols + col] = acc[m][n][j];
        }
    }
}

// ---- pass 3: per-row loss_n = adjust[n,y] + log(sum_c exp(-adjust[n,c])) ----
__global__ __launch_bounds__(256) void loss_kernel(
        const float* __restrict__ cross, const float* __restrict__ x_sq,
        const float* __restrict__ mu_sq, const int* __restrict__ y,
        float* __restrict__ loss, int C, int Cpad) {
    const int n = blockIdx.x;
    const int t = threadIdx.x;
    const int yn = y[n];
    const float xs = x_sq[n];
    const float* cr = cross + (size_t)n * Cpad;

    __shared__ float sbuf[4];
    __shared__ float spick;

    float vals[4];  // static-indexed (unrolled) -> registers
    float vmax = -3.4e38f;
#pragma unroll
    for (int i = 0; i < 4; ++i) {
        const int c = t + i * 256;
        float v = -1e30f;  // invalid slot -> exp() == 0
        if (c < C) {
            float sq = fmaxf(xs - 2.f * cr[c] + mu_sq[c], 0.f) * 0.5f;
            float dist = sqrtf(sq);
            float adj = (c == yn) ? 1.5f * dist : dist;
            if (c == yn) spick = adj;
            v = -adj;
        }
        vals[i] = v;
        vmax = fmaxf(vmax, v);
    }
    float m = vmax;
    for (int off = 32; off; off >>= 1) m = fmaxf(m, __shfl_down(m, off, 64));
    if ((t & 63) == 0) sbuf[t >> 6] = m;
    __syncthreads();
    m = fmaxf(fmaxf(sbuf[0], sbuf[1]), fmaxf(sbuf[2], sbuf[3]));

    float se = 0.f;
#pragma unroll
    for (int i = 0; i < 4; ++i) se += expf(vals[i] - m);
    for (int off = 32; off; off >>= 1) se += __shfl_down(se, off, 64);
    __syncthreads();
    if ((t & 63) == 0) sbuf[t >> 6] = se;
    __syncthreads();
    if (t == 0) {
        float lse = logf(sbuf[0] + sbuf[1] + sbuf[2] + sbuf[3]) + m;
        loss[n] = spick + lse;
    }
}

// ---- pass 4: deterministic mean (single block, no atomics) ----
__global__ __launch_bounds__(256) void reduce_kernel(
        const float* __restrict__ loss, float* __restrict__ out, int N) {
    const int t = threadIdx.x;
    float acc = 0.f;
    for (int i = t; i < N; i += 256) acc += loss[i];
    for (int off = 32; off; off >>= 1) acc += __shfl_down(acc, off, 64);
    __shared__ float sbuf[4];
    if ((t & 63) == 0) sbuf[t >> 6] = acc;
    __syncthreads();
    if (t == 0) out[0] = (sbuf[0] + sbuf[1] + sbuf[2] + sbuf[3]) / (float)N;
}

extern "C" void kernel_launch(void* const* d_in, const int* in_sizes, int n_in,
                              void* d_out, int out_size, void* d_ws, size_t ws_size,
                              hipStream_t stream) {
    const float* x  = (const float*)d_in[0];
    const int*   y  = (const int*)d_in[1];
    const float* mu = (const float*)d_in[2];

    const int N = in_sizes[1];              // 16384
    const int D = in_sizes[0] / N;          // 2048
    const int C = in_sizes[2] / D;          // 1000
    const int Cpad = ((C + 127) / 128) * 128;  // 1024

    char* ws = (char*)d_ws;
    unsigned short* x16  = (unsigned short*)ws; ws += (size_t)N * D * 2;      // 67.1 MB
    unsigned short* mu16 = (unsigned short*)ws; ws += (size_t)Cpad * D * 2;   //  4.2 MB
    float* cross = (float*)ws;                  ws += (size_t)N * Cpad * 4;   // 67.1 MB
    float* x_sq  = (float*)ws;                  ws += (size_t)N * 4;
    float* mu_sq = (float*)ws;                  ws += (size_t)Cpad * 4;
    float* lossb = (float*)ws;                  ws += (size_t)N * 4;

    convert_x_kernel<<<N, 256, 0, stream>>>(x, x16, x_sq, D);
    convert_mu_kernel<<<Cpad, 256, 0, stream>>>(mu, mu16, mu_sq, D, C);
    gemm_kernel<<<dim3(N / BM, Cpad / BN), 256, 0, stream>>>(x16, mu16, cross, N, Cpad, D);
    loss_kernel<<<N, 256, 0, stream>>>(cross, x_sq, mu_sq, y, lossb, C, Cpad);
    reduce_kernel<<<1, 256, 0, stream>>>(lossb, d_out ? (float*)d_out : nullptr, N);
}

// Round 2
// 183.980 us; speedup vs baseline: 1.0255x; 1.0255x over previous
//
#include <hip/hip_runtime.h>

typedef __bf16 bf16x8 __attribute__((ext_vector_type(8)));
typedef float  f32x4  __attribute__((ext_vector_type(4)));

__device__ inline unsigned short f32_to_bf16(float f) {
    union { float f; unsigned int u; } v; v.f = f;
    unsigned int lsb = (v.u >> 16) & 1u;
    v.u += 0x7fffu + lsb;                 // round-to-nearest-even
    return (unsigned short)(v.u >> 16);
}

__device__ inline void gload_lds16(const void* g, void* l) {
    __builtin_amdgcn_global_load_lds((const __attribute__((address_space(1))) void*)g,
                                     (__attribute__((address_space(3))) void*)l,
                                     16, 0, 0);
}

// ---- pass 1a: x f32 -> bf16, plus per-row sum of squares (f32, exact) ----
__global__ __launch_bounds__(256) void convert_x_kernel(
        const float* __restrict__ x, unsigned short* __restrict__ x16,
        float* __restrict__ x_sq, int D) {
    const int n = blockIdx.x;
    const int t = threadIdx.x;
    const float* xr = x + (size_t)n * D;
    unsigned short* xo = x16 + (size_t)n * D;
    float acc = 0.f;
    for (int p = 0; p < D / 1024; ++p) {
        const int col = p * 1024 + t * 4;
        float4 v = *(const float4*)(xr + col);
        acc += v.x * v.x + v.y * v.y + v.z * v.z + v.w * v.w;
        ushort4 o;
        o.x = f32_to_bf16(v.x); o.y = f32_to_bf16(v.y);
        o.z = f32_to_bf16(v.z); o.w = f32_to_bf16(v.w);
        *(ushort4*)(xo + col) = o;
    }
    for (int off = 32; off; off >>= 1) acc += __shfl_down(acc, off, 64);
    __shared__ float sbuf[4];
    if ((t & 63) == 0) sbuf[t >> 6] = acc;
    __syncthreads();
    if (t == 0) x_sq[n] = sbuf[0] + sbuf[1] + sbuf[2] + sbuf[3];
}

// ---- pass 1b: mu f32 -> bf16 (zero-padded to Cpad rows), plus mu_sq ----
__global__ __launch_bounds__(256) void convert_mu_kernel(
        const float* __restrict__ mu, unsigned short* __restrict__ mu16,
        float* __restrict__ mu_sq, int D, int C) {
    const int c = blockIdx.x;
    const int t = threadIdx.x;
    unsigned short* mo = mu16 + (size_t)c * D;
    if (c >= C) {
        for (int p = 0; p < D / 1024; ++p) {
            const int col = p * 1024 + t * 4;
            *(ushort4*)(mo + col) = make_ushort4(0, 0, 0, 0);
        }
        if (t == 0) mu_sq[c] = 0.f;
        return;
    }
    const float* mr = mu + (size_t)c * D;
    float acc = 0.f;
    for (int p = 0; p < D / 1024; ++p) {
        const int col = p * 1024 + t * 4;
        float4 v = *(const float4*)(mr + col);
        acc += v.x * v.x + v.y * v.y + v.z * v.z + v.w * v.w;
        ushort4 o;
        o.x = f32_to_bf16(v.x); o.y = f32_to_bf16(v.y);
        o.z = f32_to_bf16(v.z); o.w = f32_to_bf16(v.w);
        *(ushort4*)(mo + col) = o;
    }
    for (int off = 32; off; off >>= 1) acc += __shfl_down(acc, off, 64);
    __shared__ float sbuf[4];
    if ((t & 63) == 0) sbuf[t >> 6] = acc;
    __syncthreads();
    if (t == 0) mu_sq[c] = sbuf[0] + sbuf[1] + sbuf[2] + sbuf[3];
}

// ---- pass 2: 256x256x64 8-phase GEMM (T2+T3+T4+T5) with fused partial-LSE ----
// LDS per dbuf (64KB): A-kh0 @0, B-kh0 @16K, A-kh1 @32K, B-kh1 @48K, each [256][32] bf16
// swizzle: LDS slot (row, kc) holds global k-chunk kc ^ ((row>>1)&3)  (involution)
#define BM 256
#define BN 256
#define BK 64

#define MFMA16(MH) do {                                                           \
    _Pragma("unroll")                                                             \
    for (int mm = 0; mm < 4; ++mm)                                                \
        _Pragma("unroll")                                                         \
        for (int nn = 0; nn < 4; ++nn)                                            \
            acc[(MH)*4+mm][nn] = __builtin_amdgcn_mfma_f32_16x16x32_bf16(         \
                af[mm], bf[nn], acc[(MH)*4+mm][nn], 0, 0, 0);                     \
  } while (0)

#define PHASE(CB, MH, KS, LDBF, SQ, SH, VM) do {                                  \
    const char* ab = aBase + (CB)*65536 + (KS)*32768 + (MH)*4096;                 \
    af[0] = *(const bf16x8*)(ab);                                                 \
    af[1] = *(const bf16x8*)(ab + 1024);                                          \
    af[2] = *(const bf16x8*)(ab + 2048);                                          \
    af[3] = *(const bf16x8*)(ab + 3072);                                          \
    if (LDBF) {                                                                   \
        const char* bb = bBase + (CB)*65536 + (KS)*32768;                         \
        bf[0] = *(const bf16x8*)(bb);                                             \
        bf[1] = *(const bf16x8*)(bb + 1024);                                      \
        bf[2] = *(const bf16x8*)(bb + 2048);                                      \
        bf[3] = *(const bf16x8*)(bb + 3072);                                      \
    }                                                                             \
    STAGE((SQ), (SH));                                                            \
    __builtin_amdgcn_s_barrier();                                                 \
    asm volatile("s_waitcnt lgkmcnt(0)" ::: "memory");                            \
    __builtin_amdgcn_s_setprio(1);                                                \
    MFMA16(MH);                                                                   \
    __builtin_amdgcn_s_setprio(0);                                                \
    if (VM) asm volatile("s_waitcnt vmcnt(4)" ::: "memory");                      \
    __builtin_amdgcn_s_barrier();                                                 \
  } while (0)

__global__ __launch_bounds__(512, 2) void gemm_fused_kernel(
        const unsigned short* __restrict__ A,   // [M][K] bf16
        const unsigned short* __restrict__ B,   // [Cpad][K] bf16
        const float* __restrict__ x_sq, const float* __restrict__ mu_sq,
        const int* __restrict__ y,
        float* __restrict__ pM, float* __restrict__ pS, float* __restrict__ pP,
        int K, int C, int NCB) {
    __shared__ __align__(16) char smem[131072];   // 2 dbuf x 64KB
    __shared__ float part[256][4][3];             // (max, sumexp, pick) per row per wc

    const int t  = threadIdx.x;
    const int l  = t & 63, w = t >> 6;
    const int wr = w >> 2, wc = w & 3;            // 2M x 4N wave grid
    const int lr = l & 15, kh = l >> 4;
    const int rowBase = blockIdx.x * BM;
    const int colBase = blockIdx.y * BN;
    const int nt = K / BK;                        // 32 K-tiles

    // ---- staging (write side): linear LDS dest, pre-swizzled global source ----
    const int sr = w * 16 + (l >> 2);                       // local row, j adds 128
    const int kc_src = (l & 3) ^ ((l >> 3) & 3);            // = kc_slot ^ ((row>>1)&3)
    const unsigned short* gA = A + (size_t)(rowBase + sr) * K + kc_src * 8;
    const unsigned short* gB = B + (size_t)(colBase + sr) * K + kc_src * 8;
    const size_t jstride = (size_t)128 * K;
    char* ldst = smem + (size_t)t * 16;

    auto STAGE = [&](int q, int h) {
        const int qc = (q < nt) ? q : nt - 1;               // clamped: lands in dead slots
        const int cb = q & 1;
        const int ks = h >> 1;
        const unsigned short* g = (h & 1) ? gB : gA;
        const size_t goff = (size_t)qc * BK + (size_t)ks * 32;
        char* ld = ldst + cb * 65536 + h * 16384;
        gload_lds16(g + goff, ld);
        gload_lds16(g + goff + jstride, ld + 8192);
    };

    // ---- read side (swizzled ds_read, conflict-free) ----
    const int xorc = (lr >> 1) & 3;
    const int chunkb = ((kh ^ xorc) << 4);
    const char* aBase = smem + (wr * 128 + lr) * 64 + chunkb;
    const char* bBase = smem + 16384 + (wc * 64 + lr) * 64 + chunkb;

    f32x4 acc[8][4];
#pragma unroll
    for (int m = 0; m < 8; ++m)
#pragma unroll
        for (int n = 0; n < 4; ++n) acc[m][n] = (f32x4){0.f, 0.f, 0.f, 0.f};

    // prologue: tile0 (4 halves) + tile1 (h0,h1); wait all but last 2 halves
    STAGE(0, 0); STAGE(0, 1); STAGE(0, 2); STAGE(0, 3);
    STAGE(1, 0); STAGE(1, 1);
    asm volatile("s_waitcnt vmcnt(4)" ::: "memory");
    __builtin_amdgcn_s_barrier();

    bf16x8 af[4], bf[4];
#pragma unroll 1
    for (int i = 0; i < nt / 2; ++i) {
        const int tt = 2 * i;
        PHASE(0, 0, 0, 1, tt + 1, 2, 0);
        PHASE(0, 1, 0, 0, tt + 1, 3, 0);
        PHASE(0, 0, 1, 1, tt + 2, 0, 0);
        PHASE(0, 1, 1, 0, tt + 2, 1, 1);
        PHASE(1, 0, 0, 1, tt + 2, 2, 0);
        PHASE(1, 1, 0, 0, tt + 2, 3, 0);
        PHASE(1, 0, 1, 1, tt + 3, 0, 0);
        PHASE(1, 1, 1, 0, tt + 3, 1, 1);
    }

    // ---- fused epilogue: per-(row, colblock) online-LSE partials ----
    // C/D layout: col = lane&15 (lr), row = kh*4 + reg j
#pragma unroll
    for (int m = 0; m < 8; ++m) {
#pragma unroll
        for (int j = 0; j < 4; ++j) {
            const int row_l = wr * 128 + m * 16 + kh * 4 + j;
            const int grow = rowBase + row_l;
            const float xs = x_sq[grow];
            const int yr = y[grow];
            float v[4];
            float vmax = -3.4e38f, pick = -1.f;
#pragma unroll
            for (int n = 0; n < 4; ++n) {
                const int col = colBase + wc * 64 + n * 16 + lr;
                const float cr = acc[m][n][j];
                const float sq = fmaxf(xs - 2.f * cr + mu_sq[col], 0.f) * 0.5f;
                const float d = sqrtf(sq);
                const float adj = (col == yr) ? 1.5f * d : d;
                if (col == yr) pick = adj;
                v[n] = (col < C) ? -adj : -1e30f;
                vmax = fmaxf(vmax, v[n]);
            }
            for (int off = 1; off <= 8; off <<= 1)
                vmax = fmaxf(vmax, __shfl_xor(vmax, off, 64));
            float s = 0.f;
#pragma unroll
            for (int n = 0; n < 4; ++n) s += expf(v[n] - vmax);
            for (int off = 1; off <= 8; off <<= 1) s += __shfl_xor(s, off, 64);
            for (int off = 1; off <= 8; off <<= 1)
                pick = fmaxf(pick, __shfl_xor(pick, off, 64));
            if (lr == 0) {
                part[row_l][wc][0] = vmax;
                part[row_l][wc][1] = s;
                part[row_l][wc][2] = pick;
            }
        }
    }
    __syncthreads();
    if (t < 256) {
        float Mx = part[t][0][0], S = 0.f, pk = part[t][0][2];
#pragma unroll
        for (int b = 1; b < 4; ++b) Mx = fmaxf(Mx, part[t][b][0]);
#pragma unroll
        for (int b = 0; b < 4; ++b) {
            S += part[t][b][1] * expf(part[t][b][0] - Mx);
            pk = fmaxf(pk, part[t][b][2]);
        }
        const size_t o = (size_t)(rowBase + t) * NCB + blockIdx.y;
        pM[o] = Mx; pS[o] = S; pP[o] = pk;
    }
}

// ---- pass 3: merge colblock partials -> per-row loss -> per-block sum ----
__global__ __launch_bounds__(256) void loss_combine_kernel(
        const float* __restrict__ pM, const float* __restrict__ pS,
        const float* __restrict__ pP, float* __restrict__ bsum, int NCB) {
    const int t = threadIdx.x;
    const int row = blockIdx.x * 256 + t;
    float Mx = -3.4e38f;
    for (int b = 0; b < NCB; ++b) Mx = fmaxf(Mx, pM[(size_t)row * NCB + b]);
    float S = 0.f, pick = -1.f;
    for (int b = 0; b < NCB; ++b) {
        S += pS[(size_t)row * NCB + b] * expf(pM[(size_t)row * NCB + b] - Mx);
        pick = fmaxf(pick, pP[(size_t)row * NCB + b]);
    }
    float loss = pick + logf(S) + Mx;
    for (int off = 32; off; off >>= 1) loss += __shfl_down(loss, off, 64);
    __shared__ float sb[4];
    if ((t & 63) == 0) sb[t >> 6] = loss;
    __syncthreads();
    if (t == 0) bsum[blockIdx.x] = sb[0] + sb[1] + sb[2] + sb[3];
}

__global__ __launch_bounds__(64) void final_mean_kernel(
        const float* __restrict__ bsum, float* __restrict__ out, int nb, int N) {
    float a = 0.f;
    for (int i = threadIdx.x; i < nb; i += 64) a += bsum[i];
    for (int off = 32; off; off >>= 1) a += __shfl_down(a, off, 64);
    if (threadIdx.x == 0) out[0] = a / (float)N;
}

extern "C" void kernel_launch(void* const* d_in, const int* in_sizes, int n_in,
                              void* d_out, int out_size, void* d_ws, size_t ws_size,
                              hipStream_t stream) {
    const float* x  = (const float*)d_in[0];
    const int*   y  = (const int*)d_in[1];
    const float* mu = (const float*)d_in[2];

    const int N = in_sizes[1];                 // 16384
    const int D = in_sizes[0] / N;             // 2048
    const int C = in_sizes[2] / D;             // 1000
    const int Cpad = ((C + 255) / 256) * 256;  // 1024
    const int NCB = Cpad / BN;                 // 4 column blocks
    const int NRB = N / 256;                   // 64 row blocks

    char* ws = (char*)d_ws;
    unsigned short* x16  = (unsigned short*)ws; ws += (size_t)N * D * 2;      // 67.1 MB
    unsigned short* mu16 = (unsigned short*)ws; ws += (size_t)Cpad * D * 2;   //  4.2 MB
    float* x_sq  = (float*)ws;                  ws += (size_t)N * 4;
    float* mu_sq = (float*)ws;                  ws += (size_t)Cpad * 4;
    float* pM    = (float*)ws;                  ws += (size_t)N * NCB * 4;
    float* pS    = (float*)ws;                  ws += (size_t)N * NCB * 4;
    float* pP    = (float*)ws;                  ws += (size_t)N * NCB * 4;
    float* bsum  = (float*)ws;                  ws += (size_t)NRB * 4;

    convert_x_kernel<<<N, 256, 0, stream>>>(x, x16, x_sq, D);
    convert_mu_kernel<<<Cpad, 256, 0, stream>>>(mu, mu16, mu_sq, D, C);
    gemm_fused_kernel<<<dim3(N / BM, NCB), 512, 0, stream>>>(
        x16, mu16, x_sq, mu_sq, y, pM, pS, pP, D, C, NCB);
    loss_combine_kernel<<<NRB, 256, 0, stream>>>(pM, pS, pP, bsum, NCB);
    final_mean_kernel<<<1, 64, 0, stream>>>(bsum, d_out ? (float*)d_out : nullptr, N, N);
}

// Round 3
// 124.852 us; speedup vs baseline: 1.5111x; 1.4736x over previous
//
#include <hip/hip_runtime.h>

typedef __bf16 bf16x8 __attribute__((ext_vector_type(8)));
typedef float  f32x4  __attribute__((ext_vector_type(4)));

__device__ inline unsigned short f32_to_bf16(float f) {
    union { float f; unsigned int u; } v; v.f = f;
    unsigned int lsb = (v.u >> 16) & 1u;
    v.u += 0x7fffu + lsb;                 // round-to-nearest-even
    return (unsigned short)(v.u >> 16);
}

__device__ inline void gload_lds16(const void* g, void* l) {
    __builtin_amdgcn_global_load_lds((const __attribute__((address_space(1))) void*)g,
                                     (__attribute__((address_space(3))) void*)l,
                                     16, 0, 0);
}

// ---- pass 1a: x f32 -> bf16, plus per-row sum of squares (f32, exact) ----
__global__ __launch_bounds__(256) void convert_x_kernel(
        const float* __restrict__ x, unsigned short* __restrict__ x16,
        float* __restrict__ x_sq, int D) {
    const int n = blockIdx.x;
    const int t = threadIdx.x;
    const float* xr = x + (size_t)n * D;
    unsigned short* xo = x16 + (size_t)n * D;
    float acc = 0.f;
    for (int p = 0; p < D / 1024; ++p) {
        const int col = p * 1024 + t * 4;
        float4 v = *(const float4*)(xr + col);
        acc += v.x * v.x + v.y * v.y + v.z * v.z + v.w * v.w;
        ushort4 o;
        o.x = f32_to_bf16(v.x); o.y = f32_to_bf16(v.y);
        o.z = f32_to_bf16(v.z); o.w = f32_to_bf16(v.w);
        *(ushort4*)(xo + col) = o;
    }
    for (int off = 32; off; off >>= 1) acc += __shfl_down(acc, off, 64);
    __shared__ float sbuf[4];
    if ((t & 63) == 0) sbuf[t >> 6] = acc;
    __syncthreads();
    if (t == 0) x_sq[n] = sbuf[0] + sbuf[1] + sbuf[2] + sbuf[3];
}

// ---- pass 1b: mu f32 -> bf16 (zero-padded to Cpad rows), plus mu_sq ----
__global__ __launch_bounds__(256) void convert_mu_kernel(
        const float* __restrict__ mu, unsigned short* __restrict__ mu16,
        float* __restrict__ mu_sq, int D, int C) {
    const int c = blockIdx.x;
    const int t = threadIdx.x;
    unsigned short* mo = mu16 + (size_t)c * D;
    if (c >= C) {
        for (int p = 0; p < D / 1024; ++p) {
            const int col = p * 1024 + t * 4;
            *(ushort4*)(mo + col) = make_ushort4(0, 0, 0, 0);
        }
        if (t == 0) mu_sq[c] = 0.f;
        return;
    }
    const float* mr = mu + (size_t)c * D;
    float acc = 0.f;
    for (int p = 0; p < D / 1024; ++p) {
        const int col = p * 1024 + t * 4;
        float4 v = *(const float4*)(mr + col);
        acc += v.x * v.x + v.y * v.y + v.z * v.z + v.w * v.w;
        ushort4 o;
        o.x = f32_to_bf16(v.x); o.y = f32_to_bf16(v.y);
        o.z = f32_to_bf16(v.z); o.w = f32_to_bf16(v.w);
        *(ushort4*)(mo + col) = o;
    }
    for (int off = 32; off; off >>= 1) acc += __shfl_down(acc, off, 64);
    __shared__ float sbuf[4];
    if ((t & 63) == 0) sbuf[t >> 6] = acc;
    __syncthreads();
    if (t == 0) mu_sq[c] = sbuf[0] + sbuf[1] + sbuf[2] + sbuf[3];
}

// ---- pass 2: 256x256x64 8-phase GEMM (T2+T3+T4+T5) with fused partial-LSE ----
// LDS per dbuf (64KB): A-kh0 @0, B-kh0 @16K, A-kh1 @32K, B-kh1 @48K, each [256][32] bf16
// swizzle: LDS slot (row, kc) holds global k-chunk kc ^ ((row>>1)&3)  (involution)
#define BM 256
#define BN 256
#define BK 64

#define MFMA16(MH) do {                                                           \
    _Pragma("unroll")                                                             \
    for (int mm = 0; mm < 4; ++mm)                                                \
        _Pragma("unroll")                                                         \
        for (int nn = 0; nn < 4; ++nn)                                            \
            acc[(MH)*4+mm][nn] = __builtin_amdgcn_mfma_f32_16x16x32_bf16(         \
                af[mm], bf[nn], acc[(MH)*4+mm][nn], 0, 0, 0);                     \
  } while (0)

#define PHASE(CB, MH, KS, LDBF, SQ, SH, VM) do {                                  \
    const char* ab = aBase + (CB)*65536 + (KS)*32768 + (MH)*4096;                 \
    af[0] = *(const bf16x8*)(ab);                                                 \
    af[1] = *(const bf16x8*)(ab + 1024);                                          \
    af[2] = *(const bf16x8*)(ab + 2048);                                          \
    af[3] = *(const bf16x8*)(ab + 3072);                                          \
    if (LDBF) {                                                                   \
        const char* bb = bBase + (CB)*65536 + (KS)*32768;                         \
        bf[0] = *(const bf16x8*)(bb);                                             \
        bf[1] = *(const bf16x8*)(bb + 1024);                                      \
        bf[2] = *(const bf16x8*)(bb + 2048);                                      \
        bf[3] = *(const bf16x8*)(bb + 3072);                                      \
    }                                                                             \
    STAGE((SQ), (SH));                                                            \
    __builtin_amdgcn_s_barrier();                                                 \
    asm volatile("s_waitcnt lgkmcnt(0)" ::: "memory");                            \
    __builtin_amdgcn_s_setprio(1);                                                \
    MFMA16(MH);                                                                   \
    __builtin_amdgcn_s_setprio(0);                                                \
    if (VM) asm volatile("s_waitcnt vmcnt(4)" ::: "memory");                      \
    __builtin_amdgcn_s_barrier();                                                 \
  } while (0)

__global__ __launch_bounds__(512, 2) void gemm_fused_kernel(
        const unsigned short* __restrict__ A,   // [M][K] bf16
        const unsigned short* __restrict__ B,   // [Cpad][K] bf16
        const float* __restrict__ x_sq, const float* __restrict__ mu_sq,
        const int* __restrict__ y,
        float* __restrict__ pM, float* __restrict__ pS, float* __restrict__ pP,
        int K, int C, int NCB) {
    __shared__ __align__(16) char smem[131072];   // 2 dbuf x 64KB
    __shared__ float part[256][4][3];             // (max, sumexp, pick) per row per wc

    const int t  = threadIdx.x;
    const int l  = t & 63, w = t >> 6;
    const int wr = w >> 2, wc = w & 3;            // 2M x 4N wave grid
    const int lr = l & 15, kh = l >> 4;
    const int rowBase = blockIdx.x * BM;
    const int colBase = blockIdx.y * BN;
    const int nt = K / BK;                        // 32 K-tiles

    // ---- staging (write side): linear LDS dest, pre-swizzled global source ----
    const int sr = w * 16 + (l >> 2);                       // local row, j adds 128
    const int kc_src = (l & 3) ^ ((l >> 3) & 3);            // = kc_slot ^ ((row>>1)&3)
    const unsigned short* gA = A + (size_t)(rowBase + sr) * K + kc_src * 8;
    const unsigned short* gB = B + (size_t)(colBase + sr) * K + kc_src * 8;
    const size_t jstride = (size_t)128 * K;
    char* ldst = smem + (size_t)t * 16;

    auto STAGE = [&](int q, int h) {
        const int qc = (q < nt) ? q : nt - 1;               // clamped: lands in dead slots
        const int cb = q & 1;
        const int ks = h >> 1;
        const unsigned short* g = (h & 1) ? gB : gA;
        const size_t goff = (size_t)qc * BK + (size_t)ks * 32;
        char* ld = ldst + cb * 65536 + h * 16384;
        gload_lds16(g + goff, ld);
        gload_lds16(g + goff + jstride, ld + 8192);
    };

    // ---- read side (swizzled ds_read, conflict-free) ----
    const int xorc = (lr >> 1) & 3;
    const int chunkb = ((kh ^ xorc) << 4);
    const char* aBase = smem + (wr * 128 + lr) * 64 + chunkb;
    const char* bBase = smem + 16384 + (wc * 64 + lr) * 64 + chunkb;

    f32x4 acc[8][4];
#pragma unroll
    for (int m = 0; m < 8; ++m)
#pragma unroll
        for (int n = 0; n < 4; ++n) acc[m][n] = (f32x4){0.f, 0.f, 0.f, 0.f};

    // prologue: tile0 (4 halves) + tile1 (h0,h1); wait all but last 2 halves
    STAGE(0, 0); STAGE(0, 1); STAGE(0, 2); STAGE(0, 3);
    STAGE(1, 0); STAGE(1, 1);
    asm volatile("s_waitcnt vmcnt(4)" ::: "memory");
    __builtin_amdgcn_s_barrier();

    bf16x8 af[4], bf[4];
#pragma unroll 1
    for (int i = 0; i < nt / 2; ++i) {
        const int tt = 2 * i;
        PHASE(0, 0, 0, 1, tt + 1, 2, 0);
        PHASE(0, 1, 0, 0, tt + 1, 3, 0);
        PHASE(0, 0, 1, 1, tt + 2, 0, 0);
        PHASE(0, 1, 1, 0, tt + 2, 1, 1);
        PHASE(1, 0, 0, 1, tt + 2, 2, 0);
        PHASE(1, 1, 0, 0, tt + 2, 3, 0);
        PHASE(1, 0, 1, 1, tt + 3, 0, 0);
        PHASE(1, 1, 1, 0, tt + 3, 1, 1);
    }

    // ---- fused epilogue: per-(row, colblock) online-LSE partials ----
    // C/D layout: col = lane&15 (lr), row = kh*4 + reg j
#pragma unroll
    for (int m = 0; m < 8; ++m) {
#pragma unroll
        for (int j = 0; j < 4; ++j) {
            const int row_l = wr * 128 + m * 16 + kh * 4 + j;
            const int grow = rowBase + row_l;
            const float xs = x_sq[grow];
            const int yr = y[grow];
            float v[4];
            float vmax = -3.4e38f, pick = -1.f;
#pragma unroll
            for (int n = 0; n < 4; ++n) {
                const int col = colBase + wc * 64 + n * 16 + lr;
                const float cr = acc[m][n][j];
                const float sq = fmaxf(xs - 2.f * cr + mu_sq[col], 0.f) * 0.5f;
                const float d = sqrtf(sq);
                const float adj = (col == yr) ? 1.5f * d : d;
                if (col == yr) pick = adj;
                v[n] = (col < C) ? -adj : -1e30f;
                vmax = fmaxf(vmax, v[n]);
            }
            for (int off = 1; off <= 8; off <<= 1)
                vmax = fmaxf(vmax, __shfl_xor(vmax, off, 64));
            float s = 0.f;
#pragma unroll
            for (int n = 0; n < 4; ++n) s += expf(v[n] - vmax);
            for (int off = 1; off <= 8; off <<= 1) s += __shfl_xor(s, off, 64);
            for (int off = 1; off <= 8; off <<= 1)
                pick = fmaxf(pick, __shfl_xor(pick, off, 64));
            if (lr == 0) {
                part[row_l][wc][0] = vmax;
                part[row_l][wc][1] = s;
                part[row_l][wc][2] = pick;
            }
        }
    }
    __syncthreads();
    if (t < 256) {
        float Mx = part[t][0][0], S = 0.f, pk = part[t][0][2];
#pragma unroll
        for (int b = 1; b < 4; ++b) Mx = fmaxf(Mx, part[t][b][0]);
#pragma unroll
        for (int b = 0; b < 4; ++b) {
            S += part[t][b][1] * expf(part[t][b][0] - Mx);
            pk = fmaxf(pk, part[t][b][2]);
        }
        const size_t o = (size_t)(rowBase + t) * NCB + blockIdx.y;
        pM[o] = Mx; pS[o] = S; pP[o] = pk;
    }
}

// ---- pass 3: merge colblock partials -> per-row loss -> per-block sum ----
__global__ __launch_bounds__(256) void loss_combine_kernel(
        const float* __restrict__ pM, const float* __restrict__ pS,
        const float* __restrict__ pP, float* __restrict__ bsum, int NCB) {
    const int t = threadIdx.x;
    const int row = blockIdx.x * 256 + t;
    float Mx = -3.4e38f;
    for (int b = 0; b < NCB; ++b) Mx = fmaxf(Mx, pM[(size_t)row * NCB + b]);
    float S = 0.f, pick = -1.f;
    for (int b = 0; b < NCB; ++b) {
        S += pS[(size_t)row * NCB + b] * expf(pM[(size_t)row * NCB + b] - Mx);
        pick = fmaxf(pick, pP[(size_t)row * NCB + b]);
    }
    float loss = pick + logf(S) + Mx;
    for (int off = 32; off; off >>= 1) loss += __shfl_down(loss, off, 64);
    __shared__ float sb[4];
    if ((t & 63) == 0) sb[t >> 6] = loss;
    __syncthreads();
    if (t == 0) bsum[blockIdx.x] = sb[0] + sb[1] + sb[2] + sb[3];
}

__global__ __launch_bounds__(64) void final_mean_kernel(
        const float* __restrict__ bsum, float* __restrict__ out, int nb, int N) {
    float a = 0.f;
    for (int i = threadIdx.x; i < nb; i += 64) a += bsum[i];
    for (int off = 32; off; off >>= 1) a += __shfl_down(a, off, 64);
    if (threadIdx.x == 0) out[0] = a / (float)N;
}

extern "C" void kernel_launch(void* const* d_in, const int* in_sizes, int n_in,
                              void* d_out, int out_size, void* d_ws, size_t ws_size,
                              hipStream_t stream) {
    const float* x  = (const float*)d_in[0];
    const int*   y  = (const int*)d_in[1];
    const float* mu = (const float*)d_in[2];

    const int N = in_sizes[1];                 // 16384
    const int D = in_sizes[0] / N;             // 2048
    const int C = in_sizes[2] / D;             // 1000
    const int Cpad = ((C + 255) / 256) * 256;  // 1024
    const int NCB = Cpad / BN;                 // 4 column blocks
    const int NRB = N / 256;                   // 64 row blocks

    char* ws = (char*)d_ws;
    unsigned short* x16  = (unsigned short*)ws; ws += (size_t)N * D * 2;      // 67.1 MB
    unsigned short* mu16 = (unsigned short*)ws; ws += (size_t)Cpad * D * 2;   //  4.2 MB
    float* x_sq  = (float*)ws;                  ws += (size_t)N * 4;
    float* mu_sq = (float*)ws;                  ws += (size_t)Cpad * 4;
    float* pM    = (float*)ws;                  ws += (size_t)N * NCB * 4;
    float* pS    = (float*)ws;                  ws += (size_t)N * NCB * 4;
    float* pP    = (float*)ws;                  ws += (size_t)N * NCB * 4;
    float* bsum  = (float*)ws;                  ws += (size_t)NRB * 4;

    convert_x_kernel<<<N, 256, 0, stream>>>(x, x16, x_sq, D);
    convert_mu_kernel<<<Cpad, 256, 0, stream>>>(mu, mu16, mu_sq, D, C);
    gemm_fused_kernel<<<dim3(N / BM, NCB), 512, 0, stream>>>(
        x16, mu16, x_sq, mu_sq, y, pM, pS, pP, D, C, NCB);
    loss_combine_kernel<<<NRB, 256, 0, stream>>>(pM, pS, pP, bsum, NCB);
    final_mean_kernel<<<1, 64, 0, stream>>>(bsum, d_out ? (float*)d_out : nullptr, NRB, N);
}